// Round 9
// baseline (294.695 us; speedup 1.0000x reference)
//
#include <hip/hip_runtime.h>

// LSTM(H=5, in=1), T=2048, B=8192, + ReLU + FC head.
// Round 9: R8 + trans-window scheduling polish:
//  - exp issue order ui,ug,uf FIRST (uo deferred): D->rcp starts one
//    trans-slot (~17cy) earlier; uo fills the rcp window.
//  - base02 placed after R's rcp issue, base13 after wm's exp issue.
//  - MAf = M2L2E*Af pre-mul form for the (1-ug) term (same count, shorter dep).
// Structure (fixed since R6): 8 lanes/elem, 1024 waves = 1/SIMD, hw exp2/rcp,
// packed (i,g)/(f,o) matvec, scaled cell state c2=c*(-2log2e), 9-op DPP
// broadcast, 16-step unroll.

#define TLEN 2048

typedef float v2f __attribute__((ext_vector_type(2)));

__device__ __forceinline__ float fexp2(float v) { return __builtin_amdgcn_exp2f(v); }
__device__ __forceinline__ float frcp(float v)  { return __builtin_amdgcn_rcpf(v); }
__device__ __forceinline__ v2f fma2(v2f a, v2f b, v2f c) {
    return __builtin_elementwise_fma(a, b, c);
}

template<int CTRL>
__device__ __forceinline__ float dppmov(float v) {
    return __int_as_float(__builtin_amdgcn_mov_dpp(__float_as_int(v), CTRL, 0xF, 0xF, true));
}
template<int CTRL, int BANK_MASK>
__device__ __forceinline__ float dppupd(float old, float v) {
    return __int_as_float(__builtin_amdgcn_update_dpp(
        __float_as_int(old), __float_as_int(v), CTRL, 0xF, BANK_MASK, false));
}

__global__ __launch_bounds__(256, 1) void lstm_fused8u(
    const float* __restrict__ x,      // [B, T, 1]
    const float* __restrict__ W_ih,   // [20, 1]
    const float* __restrict__ W_hh,   // [20, 5]
    const float* __restrict__ b_ih,   // [20]
    const float* __restrict__ b_hh,   // [20]
    const float* __restrict__ W_fc,   // [1, 5]
    const float* __restrict__ b_fc,   // [1]
    float* __restrict__ out, int B)
{
    const int tid = blockIdx.x * 256 + threadIdx.x;
    const int b = tid >> 3;
    const int lane8 = tid & 7;
    const int k = lane8 < 5 ? lane8 : 4;   // owned hidden unit (dup lanes 5-7)

    constexpr float L2E   = 1.4426950408889634f;
    constexpr float M2L2E = -2.8853900817779268f;  // -2*log2e

    // Packed per-lane weights: pair02 = (i-row, g-row), pair13 = (f-row, o-row)
    v2f wih02, wih13, bias02, bias13, whh02[5], whh13[5];
    {
        const int ri = k, rf = 5 + k, rg = 10 + k, ro = 15 + k;
        wih02  = v2f{W_ih[ri] * -L2E,               W_ih[rg] * M2L2E};
        wih13  = v2f{W_ih[rf] * -L2E,               W_ih[ro] * -L2E};
        bias02 = v2f{(b_ih[ri] + b_hh[ri]) * -L2E,  (b_ih[rg] + b_hh[rg]) * M2L2E};
        bias13 = v2f{(b_ih[rf] + b_hh[rf]) * -L2E,  (b_ih[ro] + b_hh[ro]) * -L2E};
#pragma unroll
        for (int m = 0; m < 5; ++m) {
            whh02[m] = v2f{W_hh[ri * 5 + m] * -L2E,  W_hh[rg * 5 + m] * M2L2E};
            whh13[m] = v2f{W_hh[rf * 5 + m] * -L2E,  W_hh[ro * 5 + m] * -L2E};
        }
    }

    float c2 = 0.0f;   // scaled cell state: c * (-2*log2e)
    float h0v = 0.0f, h1v = 0.0f, h2v = 0.0f, h3v = 0.0f, h4v = 0.0f;

    const float4* xp = reinterpret_cast<const float4*>(x + (size_t)b * TLEN);
    float4 xa = xp[0], xb = xp[1], xc = xp[2], xd = xp[3];
    v2f base02 = fma2(v2f{xa.x, xa.x}, wih02, bias02);
    v2f base13 = fma2(v2f{xa.x, xa.x}, wih13, bias13);

#pragma unroll 1
    for (int t16 = 0; t16 < TLEN / 16; ++t16) {
        const int nx = (t16 + 1 < TLEN / 16) ? (t16 + 1) : t16;
        float4 na = xp[4 * nx];
        float4 nb = xp[4 * nx + 1];
        float4 nc = xp[4 * nx + 2];
        float4 nd = xp[4 * nx + 3];
        float xs[16] = {xa.y, xa.z, xa.w, xb.x, xb.y, xb.z, xb.w, xc.x,
                        xc.y, xc.z, xc.w, xd.x, xd.y, xd.z, xd.w, na.x};
#pragma unroll
        for (int q = 0; q < 16; ++q) {
            const v2f h0s = v2f{h0v, h0v}, h1s = v2f{h1v, h1v}, h2s = v2f{h2v, h2v};
            const v2f h3s = v2f{h3v, h3v}, h4s = v2f{h4v, h4v};

            // z pairs from precomputed base (split-accumulated trees)
            v2f za02 = fma2(h0s, whh02[0], base02);
            za02 = fma2(h1s, whh02[1], za02);
            v2f zb02 = fma2(h3s, whh02[3], h2s * whh02[2]);
            zb02 = fma2(h4s, whh02[4], zb02);
            const v2f z02 = za02 + zb02;         // (zi*-L2E, zg*-2L2E)

            v2f za13 = fma2(h0s, whh13[0], base13);
            za13 = fma2(h1s, whh13[1], za13);
            v2f zb13 = fma2(h3s, whh13[3], h2s * whh13[2]);
            zb13 = fma2(h4s, whh13[4], zb13);
            const v2f z13 = za13 + zb13;         // (zf*-L2E, zo*-L2E)

            // Critical-path exps first; uo (needed only at Den) deferred.
            const float ui = fexp2(z02.x);       // e^{-zi}
            const float ug = fexp2(z02.y);       // e^{-2zg}
            const float uf = fexp2(z13.x);       // e^{-zf}

            const float Ag = 1.0f + ug;
            const float Af = 1.0f + uf;
            const float P  = fmaf(ui, Ag, Ag);   // (1+ui)(1+ug)
            const float D  = P * Af;
            const float R  = frcp(D);

            // Fill the rcp window: deferred exp + next-step base (half 1).
            const float uo = fexp2(z13.y);       // e^{-zo}
            const float xn = xs[q];
            base02 = fma2(v2f{xn, xn}, wih02, bias02);

            const float MAf  = M2L2E * Af;
            const float t2vM = fmaf(-ug, MAf, MAf);   // (1-ug)*M2L2E*Af
            const float N  = fmaf(P, c2, t2vM);
            c2 = N * R;                               // scaled cell state
            const float wm = fexp2(c2);               // e^{-2c}

            // Fill the exp window: next-step base (half 2) + Ao.
            base13 = fma2(v2f{xn, xn}, wih13, bias13);
            const float Ao = 1.0f + uo;

            const float Den = fmaf(Ao, wm, Ao);       // Ao*(1+wm)
            const float Ro = frcp(Den);
            const float h  = (1.0f - wm) * Ro;        // o*tanh(c)

            // DPP broadcast of h[0..4]: 4 independent quad_perm movs first,
            // then the 5 dependent row-shift updates (hazard-friendly order).
            const float t04 = dppmov<0x00>(h);
            const float t1  = dppmov<0x55>(h);
            const float tt2 = dppmov<0xAA>(h);
            const float t3  = dppmov<0xFF>(h);
            h0v = dppupd<0x114, 0xA>(t04, t04);
            h4v = dppupd<0x104, 0x5>(t04, t04);
            h1v = dppupd<0x114, 0xA>(t1, t1);
            h2v = dppupd<0x114, 0xA>(tt2, tt2);
            h3v = dppupd<0x114, 0xA>(t3, t3);
        }
        xa = na; xb = nb; xc = nc; xd = nd;
    }

    if (lane8 == 0) {
        float acc = b_fc[0];
        acc = fmaf(fmaxf(h0v, 0.0f), W_fc[0], acc);
        acc = fmaf(fmaxf(h1v, 0.0f), W_fc[1], acc);
        acc = fmaf(fmaxf(h2v, 0.0f), W_fc[2], acc);
        acc = fmaf(fmaxf(h3v, 0.0f), W_fc[3], acc);
        acc = fmaf(fmaxf(h4v, 0.0f), W_fc[4], acc);
        out[b] = acc;
    }
}

extern "C" void kernel_launch(void* const* d_in, const int* in_sizes, int n_in,
                              void* d_out, int out_size, void* d_ws, size_t ws_size,
                              hipStream_t stream) {
    const float* x    = (const float*)d_in[0];
    const float* W_ih = (const float*)d_in[1];
    const float* W_hh = (const float*)d_in[2];
    const float* b_ih = (const float*)d_in[3];
    const float* b_hh = (const float*)d_in[4];
    const float* W_fc = (const float*)d_in[5];
    const float* b_fc = (const float*)d_in[6];
    float* out = (float*)d_out;
    const int B = out_size;  // 8192
    const int threads = B * 8;  // 65536 = 1024 waves = 1/SIMD
    lstm_fused8u<<<threads / 256, 256, 0, stream>>>(
        x, W_ih, W_hh, b_ih, b_hh, W_fc, b_fc, out, B);
}

// Round 10
// 291.485 us; speedup vs baseline: 1.0110x; 1.0110x over previous
//
#include <hip/hip_runtime.h>

// LSTM(H=5, in=1), T=2048, B=8192, + ReLU + FC head.
// FINAL (= Round 8, best measured: 230 µs/dispatch, absmax 0.0).
// Structure: 8 lanes/elem -> 1024 waves = 1 wave/SIMD (B caps wave count);
// hw exp2/rcp; packed (i,g)/(f,o) matvec (v_pk_fma_f32); scaled cell state
// c2 = c*(-2log2e) feeds the tanh exp2 directly; 9-op DPP h-broadcast;
// 16-step inner unroll.
// Proven dead-ends (measured): 16 lanes/elem (R4: +60%), VALU-emulated exp2
// (R5: +30%), source-level trans-window reordering (R9: +4%).
// Math: R=rcp(Ai*Ag*Af); c2=(P*c2+(1-ug)*M2L2E*Af)*R; P=Ai*Ag;
//       h=(1-wm)*rcp(Ao*(1+wm)), wm=exp2(c2).

#define TLEN 2048

typedef float v2f __attribute__((ext_vector_type(2)));

__device__ __forceinline__ float fexp2(float v) { return __builtin_amdgcn_exp2f(v); }
__device__ __forceinline__ float frcp(float v)  { return __builtin_amdgcn_rcpf(v); }
__device__ __forceinline__ v2f fma2(v2f a, v2f b, v2f c) {
    return __builtin_elementwise_fma(a, b, c);
}

template<int CTRL>
__device__ __forceinline__ float dppmov(float v) {
    return __int_as_float(__builtin_amdgcn_mov_dpp(__float_as_int(v), CTRL, 0xF, 0xF, true));
}
template<int CTRL, int BANK_MASK>
__device__ __forceinline__ float dppupd(float old, float v) {
    return __int_as_float(__builtin_amdgcn_update_dpp(
        __float_as_int(old), __float_as_int(v), CTRL, 0xF, BANK_MASK, false));
}

__global__ __launch_bounds__(256, 1) void lstm_fused8t(
    const float* __restrict__ x,      // [B, T, 1]
    const float* __restrict__ W_ih,   // [20, 1]
    const float* __restrict__ W_hh,   // [20, 5]
    const float* __restrict__ b_ih,   // [20]
    const float* __restrict__ b_hh,   // [20]
    const float* __restrict__ W_fc,   // [1, 5]
    const float* __restrict__ b_fc,   // [1]
    float* __restrict__ out, int B)
{
    const int tid = blockIdx.x * 256 + threadIdx.x;
    const int b = tid >> 3;
    const int lane8 = tid & 7;
    const int k = lane8 < 5 ? lane8 : 4;   // owned hidden unit (dup lanes 5-7)

    constexpr float L2E   = 1.4426950408889634f;
    constexpr float P2L2E = 2.8853900817779268f;   // +2*log2e
    constexpr float M2L2E = -2.8853900817779268f;  // -2*log2e

    // Packed per-lane weights: pair02 = (i-row, g-row), pair13 = (f-row, o-row)
    v2f wih02, wih13, bias02, bias13, whh02[5], whh13[5];
    {
        const int ri = k, rf = 5 + k, rg = 10 + k, ro = 15 + k;
        wih02  = v2f{W_ih[ri] * -L2E,               W_ih[rg] * M2L2E};
        wih13  = v2f{W_ih[rf] * -L2E,               W_ih[ro] * -L2E};
        bias02 = v2f{(b_ih[ri] + b_hh[ri]) * -L2E,  (b_ih[rg] + b_hh[rg]) * M2L2E};
        bias13 = v2f{(b_ih[rf] + b_hh[rf]) * -L2E,  (b_ih[ro] + b_hh[ro]) * -L2E};
#pragma unroll
        for (int m = 0; m < 5; ++m) {
            whh02[m] = v2f{W_hh[ri * 5 + m] * -L2E,  W_hh[rg * 5 + m] * M2L2E};
            whh13[m] = v2f{W_hh[rf * 5 + m] * -L2E,  W_hh[ro * 5 + m] * -L2E};
        }
    }

    float c2 = 0.0f;   // scaled cell state: c * (-2*log2e)
    float h0v = 0.0f, h1v = 0.0f, h2v = 0.0f, h3v = 0.0f, h4v = 0.0f;

    const float4* xp = reinterpret_cast<const float4*>(x + (size_t)b * TLEN);
    float4 xa = xp[0], xb = xp[1], xc = xp[2], xd = xp[3];
    // h-independent base for step 0
    v2f base02 = fma2(v2f{xa.x, xa.x}, wih02, bias02);
    v2f base13 = fma2(v2f{xa.x, xa.x}, wih13, bias13);

#pragma unroll 1
    for (int t16 = 0; t16 < TLEN / 16; ++t16) {
        const int nx = (t16 + 1 < TLEN / 16) ? (t16 + 1) : t16;
        float4 na = xp[4 * nx];
        float4 nb = xp[4 * nx + 1];
        float4 nc = xp[4 * nx + 2];
        float4 nd = xp[4 * nx + 3];
        // NEXT step's x for each of the 16 steps (last is dummy on final iter)
        float xs[16] = {xa.y, xa.z, xa.w, xb.x, xb.y, xb.z, xb.w, xc.x,
                        xc.y, xc.z, xc.w, xd.x, xd.y, xd.z, xd.w, na.x};
#pragma unroll
        for (int q = 0; q < 16; ++q) {
            const v2f h0s = v2f{h0v, h0v}, h1s = v2f{h1v, h1v}, h2s = v2f{h2v, h2v};
            const v2f h3s = v2f{h3v, h3v}, h4s = v2f{h4v, h4v};

            // z pairs from precomputed base (split-accumulated trees)
            v2f za02 = fma2(h0s, whh02[0], base02);
            za02 = fma2(h1s, whh02[1], za02);
            v2f zb02 = fma2(h3s, whh02[3], h2s * whh02[2]);
            zb02 = fma2(h4s, whh02[4], zb02);
            const v2f z02 = za02 + zb02;         // (zi*-L2E, zg*-2L2E)

            v2f za13 = fma2(h0s, whh13[0], base13);
            za13 = fma2(h1s, whh13[1], za13);
            v2f zb13 = fma2(h3s, whh13[3], h2s * whh13[2]);
            zb13 = fma2(h4s, whh13[4], zb13);
            const v2f z13 = za13 + zb13;         // (zf*-L2E, zo*-L2E)

            const float ui = fexp2(z02.x);       // e^{-zi}
            const float ug = fexp2(z02.y);       // e^{-2zg}
            const float uf = fexp2(z13.x);       // e^{-zf}
            const float uo = fexp2(z13.y);       // e^{-zo}

            const float Ag = 1.0f + ug;
            const float Af = 1.0f + uf;
            const float Ao = 1.0f + uo;
            const float P  = fmaf(ui, Ag, Ag);   // (1+ui)(1+ug)
            const float D  = P * Af;
            const float R  = frcp(D);

            // first half of next-step base: fills rcp latency
            const float xn = xs[q];
            base02 = fma2(v2f{xn, xn}, wih02, bias02);

            const float t2vM = fmaf(ug, P2L2E, M2L2E) * Af;  // (1-ug)*M2L2E*Af
            const float N  = fmaf(P, c2, t2vM);
            c2 = N * R;                                       // scaled cell state
            const float wm = fexp2(c2);                       // e^{-2c}
            const float Den = fmaf(Ao, wm, Ao);               // Ao*(1+wm)
            const float Ro = frcp(Den);
            const float h  = (1.0f - wm) * Ro;                // o*tanh(c)

            // second half of next-step base: covers the h->DPP hazard window
            base13 = fma2(v2f{xn, xn}, wih13, bias13);

            // DPP broadcast of h[0..4]: 4 independent quad_perm movs first,
            // then the 5 dependent row-shift updates (hazard-friendly order).
            const float t04 = dppmov<0x00>(h);
            const float t1  = dppmov<0x55>(h);
            const float tt2 = dppmov<0xAA>(h);
            const float t3  = dppmov<0xFF>(h);
            h0v = dppupd<0x114, 0xA>(t04, t04);
            h4v = dppupd<0x104, 0x5>(t04, t04);
            h1v = dppupd<0x114, 0xA>(t1, t1);
            h2v = dppupd<0x114, 0xA>(tt2, tt2);
            h3v = dppupd<0x114, 0xA>(t3, t3);
        }
        xa = na; xb = nb; xc = nc; xd = nd;
    }

    if (lane8 == 0) {
        float acc = b_fc[0];
        acc = fmaf(fmaxf(h0v, 0.0f), W_fc[0], acc);
        acc = fmaf(fmaxf(h1v, 0.0f), W_fc[1], acc);
        acc = fmaf(fmaxf(h2v, 0.0f), W_fc[2], acc);
        acc = fmaf(fmaxf(h3v, 0.0f), W_fc[3], acc);
        acc = fmaf(fmaxf(h4v, 0.0f), W_fc[4], acc);
        out[b] = acc;
    }
}

extern "C" void kernel_launch(void* const* d_in, const int* in_sizes, int n_in,
                              void* d_out, int out_size, void* d_ws, size_t ws_size,
                              hipStream_t stream) {
    const float* x    = (const float*)d_in[0];
    const float* W_ih = (const float*)d_in[1];
    const float* W_hh = (const float*)d_in[2];
    const float* b_ih = (const float*)d_in[3];
    const float* b_hh = (const float*)d_in[4];
    const float* W_fc = (const float*)d_in[5];
    const float* b_fc = (const float*)d_in[6];
    float* out = (float*)d_out;
    const int B = out_size;  // 8192
    const int threads = B * 8;  // 65536 = 1024 waves = 1/SIMD
    lstm_fused8t<<<threads / 256, 256, 0, stream>>>(
        x, W_ih, W_hh, b_ih, b_hh, W_fc, b_fc, out, B);
}